// Round 2
// baseline (1452.794 us; speedup 1.0000x reference)
//
#include <hip/hip_runtime.h>
#include <math.h>

// Problem constants
#define NSEQ 1024
#define D1C 128
#define D2C 64
#define NH 4
#define CH 32

// ---------------- reduction helpers ----------------
__device__ __forceinline__ float block_reduce_sum(float v, float* s) {
    __syncthreads();
    int lane = threadIdx.x & 63, wid = threadIdx.x >> 6;
#pragma unroll
    for (int off = 32; off > 0; off >>= 1) v += __shfl_down(v, off, 64);
    if (lane == 0) s[wid] = v;
    __syncthreads();
    float t = 0.f;
    int nw = (blockDim.x + 63) >> 6;
    for (int w = 0; w < nw; ++w) t += s[w];
    return t;
}

__device__ __forceinline__ float block_reduce_max(float v, float* s) {
    __syncthreads();
    int lane = threadIdx.x & 63, wid = threadIdx.x >> 6;
#pragma unroll
    for (int off = 32; off > 0; off >>= 1) v = fmaxf(v, __shfl_down(v, off, 64));
    if (lane == 0) s[wid] = v;
    __syncthreads();
    float t = -1e30f;
    int nw = (blockDim.x + 63) >> 6;
    for (int w = 0; w < nw; ++w) t = fmaxf(t, s[w]);
    return t;
}

// ---------------- pair mean over j ----------------
__global__ __launch_bounds__(256) void pair_mean_k(const float* __restrict__ pin,
                                                   float* __restrict__ pmean) {
    int i = blockIdx.x;
    int c4 = threadIdx.x & 15;   // float4 channel group (64 ch = 16 float4)
    int g  = threadIdx.x >> 4;   // 16 j groups
    const float4* p4 = (const float4*)(pin + ((size_t)i << 16));
    float4 acc = {0.f, 0.f, 0.f, 0.f};
    for (int j = g; j < NSEQ; j += 16) {
        float4 v = p4[j * 16 + c4];
        acc.x += v.x; acc.y += v.y; acc.z += v.z; acc.w += v.w;
    }
    __shared__ float4 s[256];
    s[threadIdx.x] = acc;
    __syncthreads();
    if (threadIdx.x < 16) {
        float4 t = {0.f, 0.f, 0.f, 0.f};
        for (int gg = 0; gg < 16; ++gg) {
            float4 v = s[gg * 16 + threadIdx.x];
            t.x += v.x; t.y += v.y; t.z += v.z; t.w += v.w;
        }
        const float inv = 1.f / 1024.f;
        t.x *= inv; t.y *= inv; t.z *= inv; t.w *= inv;
        ((float4*)(pmean + i * 64))[threadIdx.x] = t;
    }
}

// ---------------- LayerNorm over 128 channels (optional residual add) ----------------
__global__ __launch_bounds__(128) void ln128_k(const float* __restrict__ x,
                                               const float* __restrict__ g,
                                               const float* __restrict__ b,
                                               const float* __restrict__ res,
                                               float* __restrict__ out) {
    __shared__ float sw[4];
    int i = blockIdx.x, tid = threadIdx.x;
    float v = x[i * D1C + tid];
    float m = block_reduce_sum(v, sw) * (1.f / 128.f);
    float d = v - m;
    float var = block_reduce_sum(d * d, sw) * (1.f / 128.f);
    float y = d * rsqrtf(var + 1e-5f) * g[tid] + b[tid];
    if (res) y += res[i * D1C + tid];
    out[i * D1C + tid] = y;
}

// ---------------- row-block GEMM: out[i,o] = act(in[i,:]@W + bias) (+res) ----------------
// 4 rows per block, 256 threads. W is (K, NOUT) row-major.
template <int K, int NOUT, int ACT>  // ACT: 0=none, 1=exact gelu
__global__ __launch_bounds__(256) void gemm_rows_k(const float* __restrict__ in,
                                                   const float* __restrict__ W,
                                                   const float* __restrict__ bias,
                                                   const float* __restrict__ res,
                                                   float* __restrict__ out) {
    int row0 = blockIdx.x * 4;
    __shared__ float s_in[4][K];
    for (int idx = threadIdx.x; idx < 4 * K; idx += 256) {
        int r = idx / K, k = idx % K;
        s_in[r][k] = in[(row0 + r) * K + k];
    }
    __syncthreads();
    for (int o = threadIdx.x; o < NOUT; o += 256) {
        float a0 = 0.f, a1 = 0.f, a2 = 0.f, a3 = 0.f;
#pragma unroll 4
        for (int k = 0; k < K; ++k) {
            float w = W[k * NOUT + o];
            a0 += s_in[0][k] * w;
            a1 += s_in[1][k] * w;
            a2 += s_in[2][k] * w;
            a3 += s_in[3][k] * w;
        }
        float accs[4] = {a0, a1, a2, a3};
        float bb = bias ? bias[o] : 0.f;
#pragma unroll
        for (int r = 0; r < 4; ++r) {
            float v = accs[r] + bb;
            if (ACT == 1) v = 0.5f * v * (1.f + erff(v * 0.70710678118f));
            if (res) v += res[(row0 + r) * NOUT + o];
            out[(row0 + r) * NOUT + o] = v;
        }
    }
}

// ---------------- MHA attention: one block per (i,h) ----------------
__global__ __launch_bounds__(256) void mha_attn_k(const float* __restrict__ qkv,
                                                  float* __restrict__ aout) {
    int i = blockIdx.x >> 2, h = blockIdx.x & 3;
    __shared__ float s_q[32];
    __shared__ float s_p[NSEQ];
    __shared__ float s_r[256];
    __shared__ float sw[8];
    int tid = threadIdx.x;
    if (tid < 32) s_q[tid] = qkv[i * 384 + h * 32 + tid];
    __syncthreads();
    float lv[4];
    float lmax = -1e30f;
#pragma unroll
    for (int it = 0; it < 4; ++it) {
        int j = tid + it * 256;
        const float4* kj = (const float4*)(qkv + j * 384 + 128 + h * 32);
        float dot = 0.f;
#pragma unroll
        for (int c4 = 0; c4 < 8; ++c4) {
            float4 kvv = kj[c4];
            dot += s_q[c4 * 4 + 0] * kvv.x + s_q[c4 * 4 + 1] * kvv.y +
                   s_q[c4 * 4 + 2] * kvv.z + s_q[c4 * 4 + 3] * kvv.w;
        }
        float l = dot * 0.17677669529f;  // 1/sqrt(32)
        lv[it] = l;
        lmax = fmaxf(lmax, l);
    }
    lmax = block_reduce_max(lmax, sw);
    float lsum = 0.f;
#pragma unroll
    for (int it = 0; it < 4; ++it) {
        float e = __expf(lv[it] - lmax);
        s_p[tid + it * 256] = e;
        lsum += e;
    }
    lsum = block_reduce_sum(lsum, sw);  // also makes s_p visible
    float inv = 1.f / lsum;
    int c = tid & 31, g = tid >> 5;
    float acc = 0.f;
    const float* vbase = qkv + 256 + h * 32 + c;
    for (int j = g * 128; j < g * 128 + 128; ++j) acc += s_p[j] * vbase[j * 384];
    s_r[tid] = acc;
    __syncthreads();
    if (tid < 32) {
        float s = 0.f;
#pragma unroll
        for (int gg = 0; gg < 8; ++gg) s += s_r[gg * 32 + tid];
        aout[i * 128 + h * 32 + tid] = s * inv;
    }
}

// ---------------- pair update: out = p' + p'@Wc + bc, p' = pair + outer ----------------
__global__ __launch_bounds__(256) void pair_update_k(const float* __restrict__ pin,
                                                     const float* __restrict__ left,
                                                     const float* __restrict__ right,
                                                     const float* __restrict__ wconv,
                                                     const float* __restrict__ bconv,
                                                     float* __restrict__ pout) {
    int i = blockIdx.x >> 4;
    int j0 = (blockIdx.x & 15) << 6;  // 64 j rows per block
    int c = threadIdx.x & 63;
    int r = threadIdx.x >> 6;  // 0..3
    __shared__ float s_w[64 * 64];
    __shared__ float s_p[4 * 64];
    for (int idx = threadIdx.x; idx < 4096; idx += 256) s_w[idx] = wconv[idx];
    float lf = (c < 32) ? left[i * 32 + c] : 0.f;
    float bc = bconv[c];
    __syncthreads();
    for (int t = 0; t < 16; ++t) {
        int j = j0 + t * 4 + r;
        size_t off = ((((size_t)i << 10) + j) << 6) + c;
        float p = pin[off];
        if (c < 32) p += lf + right[j * 32 + c];
        s_p[r * 64 + c] = p;
        __syncthreads();
        float acc = bc;
#pragma unroll
        for (int k = 0; k < 64; ++k) acc += s_p[r * 64 + k] * s_w[k * 64 + c];
        pout[off] = p + acc;
        __syncthreads();
    }
}

// ---------------- IPA: local->global frames + qq/kk ----------------
__global__ __launch_bounds__(256) void to_global_k(const float* __restrict__ qp,
                                                   const float* __restrict__ kp,
                                                   const float* __restrict__ vp,
                                                   const float* __restrict__ R,
                                                   const float* __restrict__ t,
                                                   float* __restrict__ qpg,
                                                   float* __restrict__ kpg,
                                                   float* __restrict__ vpg,
                                                   float* __restrict__ qq,
                                                   float* __restrict__ kk) {
    int i = blockIdx.x, tid = threadIdx.x;
    __shared__ float sR[9], sT[3], sG[96];
    if (tid < 9) sR[tid] = R[i * 9 + tid];
    if (tid < 3) sT[tid] = t[i * 3 + tid];
    __syncthreads();
    if (tid < 144) {
        int tensor = tid / 48, rem = tid % 48;
        int comp = rem % 3, base = rem - comp;
        const float* in = (tensor == 0) ? qp : ((tensor == 1) ? kp : vp);
        float v = sT[comp];
#pragma unroll
        for (int jj = 0; jj < 3; ++jj) v += sR[comp * 3 + jj] * in[i * 48 + base + jj];
        float* outp = (tensor == 0) ? qpg : ((tensor == 1) ? kpg : vpg);
        outp[i * 48 + rem] = v;
        if (tensor < 2) sG[tensor * 48 + rem] = v;
    }
    __syncthreads();
    if (tid < 8) {
        int tensor = tid >> 2, h = tid & 3;
        float s = 0.f;
#pragma unroll
        for (int e = 0; e < 12; ++e) {
            float v = sG[tensor * 48 + h * 12 + e];
            s += v * v;
        }
        (tensor == 0 ? qq : kk)[i * 4 + h] = s;
    }
}

// ---------------- IPA attention: one block per (i,h) ----------------
__global__ __launch_bounds__(256) void ipa_attn_k(const float* __restrict__ q,
                                                  const float* __restrict__ k,
                                                  const float* __restrict__ v,
                                                  const float* __restrict__ qpg,
                                                  const float* __restrict__ kpg,
                                                  const float* __restrict__ vpg,
                                                  const float* __restrict__ qq,
                                                  const float* __restrict__ kk,
                                                  const float* __restrict__ headw,
                                                  float* __restrict__ feat,
                                                  float* __restrict__ optg) {
    int i = blockIdx.x >> 2, h = blockIdx.x & 3;
    __shared__ float s_q[32], s_qp[12], s_p[NSEQ], s_r[256], sw[8], s_sc[2];
    int tid = threadIdx.x;
    if (tid < 32) s_q[tid] = q[i * 128 + h * 32 + tid];
    if (tid < 12) s_qp[tid] = qpg[i * 48 + h * 12 + tid];
    if (tid == 0) {
        s_sc[0] = qq[i * 4 + h];
        float gamma = log1pf(__expf(headw[h]));  // softplus
        s_sc[1] = gamma * 0.23570226039f * 0.5f;  // gamma * wC * 0.5, wC=sqrt(1/18)
    }
    __syncthreads();
    float qqv = s_sc[0], coef = s_sc[1];
    float lv[4];
    float lmax = -1e30f;
#pragma unroll
    for (int it = 0; it < 4; ++it) {
        int j = tid + it * 256;
        const float4* kj = (const float4*)(k + j * 128 + h * 32);
        float dot = 0.f;
#pragma unroll
        for (int c4 = 0; c4 < 8; ++c4) {
            float4 kvv = kj[c4];
            dot += s_q[c4 * 4 + 0] * kvv.x + s_q[c4 * 4 + 1] * kvv.y +
                   s_q[c4 * 4 + 2] * kvv.z + s_q[c4 * 4 + 3] * kvv.w;
        }
        float scalar = dot * 0.17677669529f;
        const float* kpj = kpg + j * 48 + h * 12;
        float d12 = 0.f;
#pragma unroll
        for (int e = 0; e < 12; ++e) d12 += s_qp[e] * kpj[e];
        float d2 = qqv + kk[j * 4 + h] - 2.f * d12;
        float l = 0.70710678118f * (scalar - coef * d2);
        lv[it] = l;
        lmax = fmaxf(lmax, l);
    }
    lmax = block_reduce_max(lmax, sw);
    float lsum = 0.f;
#pragma unroll
    for (int it = 0; it < 4; ++it) {
        float e = __expf(lv[it] - lmax);
        s_p[tid + it * 256] = e;
        lsum += e;
    }
    lsum = block_reduce_sum(lsum, sw);
    float inv = 1.f / lsum;
    // o part (32 channels)
    int c = tid & 31, g = tid >> 5;
    float acc = 0.f;
    const float* vbase = v + h * 32 + c;
    for (int j = g * 128; j < g * 128 + 128; ++j) acc += s_p[j] * vbase[j * 128];
    s_r[tid] = acc;
    __syncthreads();
    if (tid < 32) {
        float s = 0.f;
#pragma unroll
        for (int gg = 0; gg < 8; ++gg) s += s_r[gg * 32 + tid];
        feat[i * 192 + h * 32 + tid] = s * inv;
    }
    // opt part (12 dims, global frame)
    __syncthreads();
    int e2 = tid & 15, g2 = tid >> 4;
    float acc2 = 0.f;
    if (e2 < 12) {
        const float* vpb = vpg + h * 12 + e2;
        for (int j = g2 * 64; j < g2 * 64 + 64; ++j) acc2 += s_p[j] * vpb[j * 48];
    }
    s_r[tid] = acc2;
    __syncthreads();
    if (tid < 12) {
        float s = 0.f;
#pragma unroll
        for (int gg = 0; gg < 16; ++gg) s += s_r[gg * 16 + tid];
        optg[i * 48 + h * 12 + tid] = s * inv;
    }
}

// ---------------- opt -> local frame + norms -> feat tail ----------------
__global__ __launch_bounds__(64) void feat_finish_k(const float* __restrict__ optg,
                                                    const float* __restrict__ R,
                                                    const float* __restrict__ t,
                                                    float* __restrict__ feat) {
    int i = blockIdx.x, tid = threadIdx.x;
    __shared__ float sR[9], sT[3], sL[48];
    if (tid < 9) sR[tid] = R[i * 9 + tid];
    if (tid < 3) sT[tid] = t[i * 3 + tid];
    __syncthreads();
    if (tid < 48) {
        int comp = tid % 3, base = tid - comp;
        float v = 0.f;
#pragma unroll
        for (int jj = 0; jj < 3; ++jj)
            v += sR[jj * 3 + comp] * (optg[i * 48 + base + jj] - sT[jj]);
        sL[tid] = v;
        feat[i * 192 + 128 + tid] = v;
    }
    __syncthreads();
    if (tid < 16) {
        float s = 1e-8f;
#pragma unroll
        for (int comp = 0; comp < 3; ++comp) {
            float v = sL[tid * 3 + comp];
            s += v * v;
        }
        feat[i * 192 + 176 + tid] = sqrtf(s);
    }
}

// ---------------- frames pass-through ----------------
__global__ __launch_bounds__(256) void copy_frames_k(const float* __restrict__ R,
                                                     const float* __restrict__ t,
                                                     float* __restrict__ out) {
    int idx = blockIdx.x * 256 + threadIdx.x;
    if (idx < 9216) out[idx] = R[idx];
    else if (idx < 12288) out[idx] = t[idx - 9216];
}

extern "C" void kernel_launch(void* const* d_in, const int* in_sizes, int n_in,
                              void* d_out, int out_size, void* d_ws, size_t ws_size,
                              hipStream_t stream) {
    const float* seq    = (const float*)d_in[0];
    const float* pair   = (const float*)d_in[1];
    const float* fR     = (const float*)d_in[2];
    const float* ft     = (const float*)d_in[3];
    const float* ln1g   = (const float*)d_in[4];
    const float* ln1b   = (const float*)d_in[5];
    const float* w_qkv  = (const float*)d_in[6];
    const float* b_qkv  = (const float*)d_in[7];
    const float* w_o    = (const float*)d_in[8];
    const float* b_o    = (const float*)d_in[9];
    const float* w_2to1 = (const float*)d_in[10];
    const float* b_2to1 = (const float*)d_in[11];
    const float* lnffg  = (const float*)d_in[12];
    const float* lnffb  = (const float*)d_in[13];
    const float* w_ff1  = (const float*)d_in[14];
    const float* b_ff1  = (const float*)d_in[15];
    const float* w_ff2  = (const float*)d_in[16];
    const float* b_ff2  = (const float*)d_in[17];
    const float* w_l    = (const float*)d_in[18];
    const float* b_l    = (const float*)d_in[19];
    const float* w_r    = (const float*)d_in[20];
    const float* b_r    = (const float*)d_in[21];
    const float* w_conv = (const float*)d_in[22];
    const float* b_conv = (const float*)d_in[23];
    const float* wq     = (const float*)d_in[24];
    const float* wk     = (const float*)d_in[25];
    const float* wv     = (const float*)d_in[26];
    const float* wqp    = (const float*)d_in[27];
    const float* wkp    = (const float*)d_in[28];
    const float* wvp    = (const float*)d_in[29];
    const float* headw  = (const float*)d_in[30];
    const float* wout   = (const float*)d_in[31];
    const float* bout   = (const float*)d_in[32];
    const float* ln3g   = (const float*)d_in[33];
    const float* ln3b   = (const float*)d_in[34];

    float* ws = (float*)d_ws;
    float* xn      = ws; ws += 131072;
    float* qkvb    = ws; ws += 393216;
    float* abuf    = ws; ws += 131072;
    float* x1      = ws; ws += 131072;
    float* x2      = ws; ws += 131072;
    float* hdn     = ws; ws += 131072;
    float* ff1     = ws; ws += 524288;
    float* xa      = ws; ws += 131072;
    float* pmean   = ws; ws += 65536;
    float* left    = ws; ws += 32768;
    float* right   = ws; ws += 32768;
    float* qb      = ws; ws += 131072;
    float* kb      = ws; ws += 131072;
    float* vb      = ws; ws += 131072;
    float* qp      = ws; ws += 49152;
    float* kp      = ws; ws += 49152;
    float* vp      = ws; ws += 49152;
    float* qpg     = ws; ws += 49152;
    float* kpg     = ws; ws += 49152;
    float* vpg     = ws; ws += 49152;
    float* qqb     = ws; ws += 4096;
    float* kkb     = ws; ws += 4096;
    float* feat    = ws; ws += 196608;
    float* optg    = ws; ws += 49152;
    float* ipa_out = ws; ws += 131072;

    float* out_x    = (float*)d_out;
    float* out_pair = out_x + 131072;
    float* out_R    = out_pair + 67108864;
    float* out_t    = out_R + 9216;

    const int N = NSEQ;

    // pair mean over j (biggest single read; launch first)
    pair_mean_k<<<N, 256, 0, stream>>>(pair, pmean);

    // 1D track: pre-LN MHA
    ln128_k<<<N, 128, 0, stream>>>(seq, ln1g, ln1b, nullptr, xn);
    gemm_rows_k<128, 384, 0><<<N / 4, 256, 0, stream>>>(xn, w_qkv, b_qkv, nullptr, qkvb);
    mha_attn_k<<<N * NH, 256, 0, stream>>>(qkvb, abuf);
    gemm_rows_k<128, 128, 0><<<N / 4, 256, 0, stream>>>(abuf, w_o, b_o, seq, x1);

    // pair -> 1D aggregation
    gemm_rows_k<64, 128, 0><<<N / 4, 256, 0, stream>>>(pmean, w_2to1, b_2to1, x1, x2);

    // FFN
    ln128_k<<<N, 128, 0, stream>>>(x2, lnffg, lnffb, nullptr, hdn);
    gemm_rows_k<128, 512, 1><<<N / 4, 256, 0, stream>>>(hdn, w_ff1, b_ff1, nullptr, ff1);
    gemm_rows_k<512, 128, 0><<<N / 4, 256, 0, stream>>>(ff1, w_ff2, b_ff2, x2, xa);

    // 1D -> pair outer update inputs
    gemm_rows_k<128, 32, 0><<<N / 4, 256, 0, stream>>>(xa, w_l, b_l, nullptr, left);
    gemm_rows_k<128, 32, 0><<<N / 4, 256, 0, stream>>>(xa, w_r, b_r, nullptr, right);

    // pair outer + 1x1 conv (fused, single pass over pair)
    pair_update_k<<<N * 16, 256, 0, stream>>>(pair, left, right, w_conv, b_conv, out_pair);

    // IPA projections
    gemm_rows_k<128, 128, 0><<<N / 4, 256, 0, stream>>>(xa, wq, nullptr, nullptr, qb);
    gemm_rows_k<128, 128, 0><<<N / 4, 256, 0, stream>>>(xa, wk, nullptr, nullptr, kb);
    gemm_rows_k<128, 128, 0><<<N / 4, 256, 0, stream>>>(xa, wv, nullptr, nullptr, vb);
    gemm_rows_k<128, 48, 0><<<N / 4, 256, 0, stream>>>(xa, wqp, nullptr, nullptr, qp);
    gemm_rows_k<128, 48, 0><<<N / 4, 256, 0, stream>>>(xa, wkp, nullptr, nullptr, kp);
    gemm_rows_k<128, 48, 0><<<N / 4, 256, 0, stream>>>(xa, wvp, nullptr, nullptr, vp);

    // frames to global + squared sums
    to_global_k<<<N, 256, 0, stream>>>(qp, kp, vp, fR, ft, qpg, kpg, vpg, qqb, kkb);

    // IPA attention
    ipa_attn_k<<<N * NH, 256, 0, stream>>>(qb, kb, vb, qpg, kpg, vpg, qqb, kkb, headw,
                                           feat, optg);

    // local frame + norms -> feat tail
    feat_finish_k<<<N, 64, 0, stream>>>(optg, fR, ft, feat);

    // IPA output projection
    gemm_rows_k<192, 128, 0><<<N / 4, 256, 0, stream>>>(feat, wout, bout, nullptr, ipa_out);

    // final residual + post-LN
    ln128_k<<<N, 128, 0, stream>>>(ipa_out, ln3g, ln3b, xa, out_x);

    // frames pass-through
    copy_frames_k<<<48, 256, 0, stream>>>(fR, ft, out_t - 9216);
}

// Round 4
// 1182.674 us; speedup vs baseline: 1.2284x; 1.2284x over previous
//
#include <hip/hip_runtime.h>
#include <math.h>

// Problem constants
#define NSEQ 1024
#define D1C 128
#define D2C 64
#define NH 4
#define CH 32

typedef __attribute__((ext_vector_type(8))) short bf16x8;
typedef __attribute__((ext_vector_type(4))) float f32x4;

__device__ __forceinline__ short f2bf(float f) {
    unsigned u = __float_as_uint(f);
    unsigned r = (u + 0x7fffu + ((u >> 16) & 1u)) >> 16;  // RNE
    return (short)r;
}

// ---------------- reduction helpers ----------------
__device__ __forceinline__ float block_reduce_sum(float v, float* s) {
    __syncthreads();
    int lane = threadIdx.x & 63, wid = threadIdx.x >> 6;
#pragma unroll
    for (int off = 32; off > 0; off >>= 1) v += __shfl_down(v, off, 64);
    if (lane == 0) s[wid] = v;
    __syncthreads();
    float t = 0.f;
    int nw = (blockDim.x + 63) >> 6;
    for (int w = 0; w < nw; ++w) t += s[w];
    return t;
}

__device__ __forceinline__ float block_reduce_max(float v, float* s) {
    __syncthreads();
    int lane = threadIdx.x & 63, wid = threadIdx.x >> 6;
#pragma unroll
    for (int off = 32; off > 0; off >>= 1) v = fmaxf(v, __shfl_down(v, off, 64));
    if (lane == 0) s[wid] = v;
    __syncthreads();
    float t = -1e30f;
    int nw = (blockDim.x + 63) >> 6;
    for (int w = 0; w < nw; ++w) t = fmaxf(t, s[w]);
    return t;
}

// ---------------- pair mean over j ----------------
__global__ __launch_bounds__(256) void pair_mean_k(const float* __restrict__ pin,
                                                   float* __restrict__ pmean) {
    int i = blockIdx.x;
    int c4 = threadIdx.x & 15;   // float4 channel group (64 ch = 16 float4)
    int g  = threadIdx.x >> 4;   // 16 j groups
    const float4* p4 = (const float4*)(pin + ((size_t)i << 16));
    float4 acc = {0.f, 0.f, 0.f, 0.f};
    for (int j = g; j < NSEQ; j += 16) {
        float4 v = p4[j * 16 + c4];
        acc.x += v.x; acc.y += v.y; acc.z += v.z; acc.w += v.w;
    }
    __shared__ float4 s[256];
    s[threadIdx.x] = acc;
    __syncthreads();
    if (threadIdx.x < 16) {
        float4 t = {0.f, 0.f, 0.f, 0.f};
        for (int gg = 0; gg < 16; ++gg) {
            float4 v = s[gg * 16 + threadIdx.x];
            t.x += v.x; t.y += v.y; t.z += v.z; t.w += v.w;
        }
        const float inv = 1.f / 1024.f;
        t.x *= inv; t.y *= inv; t.z *= inv; t.w *= inv;
        ((float4*)(pmean + i * 64))[threadIdx.x] = t;
    }
}

// ---------------- LayerNorm over 128 channels (optional residual add) ----------------
__global__ __launch_bounds__(128) void ln128_k(const float* __restrict__ x,
                                               const float* __restrict__ g,
                                               const float* __restrict__ b,
                                               const float* __restrict__ res,
                                               float* __restrict__ out) {
    __shared__ float sw[4];
    int i = blockIdx.x, tid = threadIdx.x;
    float v = x[i * D1C + tid];
    float m = block_reduce_sum(v, sw) * (1.f / 128.f);
    float d = v - m;
    float var = block_reduce_sum(d * d, sw) * (1.f / 128.f);
    float y = d * rsqrtf(var + 1e-5f) * g[tid] + b[tid];
    if (res) y += res[i * D1C + tid];
    out[i * D1C + tid] = y;
}

// ---------------- row-block GEMM: out[i,o] = act(in[i,:]@W + bias) (+res) ----------------
template <int K, int NOUT, int ACT>  // ACT: 0=none, 1=exact gelu
__global__ __launch_bounds__(256) void gemm_rows_k(const float* __restrict__ in,
                                                   const float* __restrict__ W,
                                                   const float* __restrict__ bias,
                                                   const float* __restrict__ res,
                                                   float* __restrict__ out) {
    int row0 = blockIdx.x * 4;
    __shared__ float s_in[4][K];
    for (int idx = threadIdx.x; idx < 4 * K; idx += 256) {
        int r = idx / K, k = idx % K;
        s_in[r][k] = in[(row0 + r) * K + k];
    }
    __syncthreads();
    for (int o = threadIdx.x; o < NOUT; o += 256) {
        float a0 = 0.f, a1 = 0.f, a2 = 0.f, a3 = 0.f;
#pragma unroll 4
        for (int k = 0; k < K; ++k) {
            float w = W[k * NOUT + o];
            a0 += s_in[0][k] * w;
            a1 += s_in[1][k] * w;
            a2 += s_in[2][k] * w;
            a3 += s_in[3][k] * w;
        }
        float accs[4] = {a0, a1, a2, a3};
        float bb = bias ? bias[o] : 0.f;
#pragma unroll
        for (int r = 0; r < 4; ++r) {
            float v = accs[r] + bb;
            if (ACT == 1) v = 0.5f * v * (1.f + erff(v * 0.70710678118f));
            if (res) v += res[(row0 + r) * NOUT + o];
            out[(row0 + r) * NOUT + o] = v;
        }
    }
}

// ---------------- fused projections from xa: q,k,v,qp,kp,vp,left,right ----------------
__global__ __launch_bounds__(256) void proj_all_k(
    const float* __restrict__ xa,
    const float* __restrict__ wq, const float* __restrict__ wk, const float* __restrict__ wv,
    const float* __restrict__ wqp, const float* __restrict__ wkp, const float* __restrict__ wvp,
    const float* __restrict__ w_l, const float* __restrict__ b_l,
    const float* __restrict__ w_r, const float* __restrict__ b_r,
    float* __restrict__ qb, float* __restrict__ kb, float* __restrict__ vb,
    float* __restrict__ qp, float* __restrict__ kp, float* __restrict__ vp,
    float* __restrict__ left, float* __restrict__ right) {
    int row0 = blockIdx.x * 4;
    __shared__ float s_in[4][128];
    for (int idx = threadIdx.x; idx < 512; idx += 256)
        s_in[idx >> 7][idx & 127] = xa[row0 * 128 + idx];
    __syncthreads();
    for (int o = threadIdx.x; o < 592; o += 256) {
        const float* W; float* dst; int no, oc; float bb = 0.f;
        if (o < 384) {
            int sel = o >> 7; oc = o & 127; no = 128;
            W = sel == 0 ? wq : (sel == 1 ? wk : wv);
            dst = sel == 0 ? qb : (sel == 1 ? kb : vb);
        } else if (o < 528) {
            int r = o - 384; int sel = r / 48; oc = r % 48; no = 48;
            W = sel == 0 ? wqp : (sel == 1 ? wkp : wvp);
            dst = sel == 0 ? qp : (sel == 1 ? kp : vp);
        } else if (o < 560) {
            oc = o - 528; no = 32; W = w_l; dst = left; bb = b_l[oc];
        } else {
            oc = o - 560; no = 32; W = w_r; dst = right; bb = b_r[oc];
        }
        float a0 = 0.f, a1 = 0.f, a2 = 0.f, a3 = 0.f;
#pragma unroll 4
        for (int k = 0; k < 128; ++k) {
            float w = W[k * no + oc];
            a0 += s_in[0][k] * w;
            a1 += s_in[1][k] * w;
            a2 += s_in[2][k] * w;
            a3 += s_in[3][k] * w;
        }
        dst[(row0 + 0) * no + oc] = a0 + bb;
        dst[(row0 + 1) * no + oc] = a1 + bb;
        dst[(row0 + 2) * no + oc] = a2 + bb;
        dst[(row0 + 3) * no + oc] = a3 + bb;
    }
}

// ---------------- MHA attention: one block per (i,h) ----------------
__global__ __launch_bounds__(256) void mha_attn_k(const float* __restrict__ qkv,
                                                  float* __restrict__ aout) {
    int i = blockIdx.x >> 2, h = blockIdx.x & 3;
    __shared__ float s_q[32];
    __shared__ float s_p[NSEQ];
    __shared__ float s_r[256];
    __shared__ float sw[8];
    int tid = threadIdx.x;
    if (tid < 32) s_q[tid] = qkv[i * 384 + h * 32 + tid];
    __syncthreads();
    float lv[4];
    float lmax = -1e30f;
#pragma unroll
    for (int it = 0; it < 4; ++it) {
        int j = tid + it * 256;
        const float4* kj = (const float4*)(qkv + j * 384 + 128 + h * 32);
        float dot = 0.f;
#pragma unroll
        for (int c4 = 0; c4 < 8; ++c4) {
            float4 kvv = kj[c4];
            dot += s_q[c4 * 4 + 0] * kvv.x + s_q[c4 * 4 + 1] * kvv.y +
                   s_q[c4 * 4 + 2] * kvv.z + s_q[c4 * 4 + 3] * kvv.w;
        }
        float l = dot * 0.17677669529f;  // 1/sqrt(32)
        lv[it] = l;
        lmax = fmaxf(lmax, l);
    }
    lmax = block_reduce_max(lmax, sw);
    float lsum = 0.f;
#pragma unroll
    for (int it = 0; it < 4; ++it) {
        float e = __expf(lv[it] - lmax);
        s_p[tid + it * 256] = e;
        lsum += e;
    }
    lsum = block_reduce_sum(lsum, sw);  // also makes s_p visible
    float inv = 1.f / lsum;
    int c = tid & 31, g = tid >> 5;
    float acc = 0.f;
    const float* vbase = qkv + 256 + h * 32 + c;
    for (int j = g * 128; j < g * 128 + 128; ++j) acc += s_p[j] * vbase[j * 384];
    s_r[tid] = acc;
    __syncthreads();
    if (tid < 32) {
        float s = 0.f;
#pragma unroll
        for (int gg = 0; gg < 8; ++gg) s += s_r[gg * 32 + tid];
        aout[i * 128 + h * 32 + tid] = s * inv;
    }
}

// ---------------- pair update via MFMA: out = p' + p'@Wc + bc, p' = pair + outer ----------------
// One block per i (1024 j-rows); 4 waves, each streams 16-row strips. No LDS, no barriers.
__global__ __launch_bounds__(256) void pair_update_mfma_k(
    const float* __restrict__ pin,
    const float* __restrict__ left,    // [N][32]
    const float* __restrict__ right,   // [N][32]
    const float* __restrict__ wconv,   // [64][64]
    const float* __restrict__ bconv,   // [64]
    float* __restrict__ pout) {
    int i = blockIdx.x;
    int tid = threadIdx.x;
    int w = tid >> 6;
    int l = tid & 63;
    int lrow = l & 15;        // A row / B col / C col index
    int kgrp = l >> 4;        // 0..3
    int koff = kgrp * 8;      // k-offset within 32-wide half

    // B fragments of W (2 k-halves x 4 n-blocks), held in VGPRs for the whole block
    bf16x8 Bf[2][4];
#pragma unroll
    for (int kh = 0; kh < 2; ++kh)
#pragma unroll
        for (int nb = 0; nb < 4; ++nb) {
            int col = nb * 16 + lrow;
            bf16x8 bf;
#pragma unroll
            for (int e = 0; e < 8; ++e)
                bf[e] = f2bf(wconv[(kh * 32 + koff + e) * 64 + col]);
            Bf[kh][nb] = bf;
        }
    // left slice for the A-side outer add (channels koff..koff+7, all < 32)
    float lfA[8];
    {
        float4 l0 = *(const float4*)(left + i * 32 + koff);
        float4 l1 = *(const float4*)(left + i * 32 + koff + 4);
        lfA[0] = l0.x; lfA[1] = l0.y; lfA[2] = l0.z; lfA[3] = l0.w;
        lfA[4] = l1.x; lfA[5] = l1.y; lfA[6] = l1.z; lfA[7] = l1.w;
    }
    // epilogue per-nb constants
    float biasc[4], leftc[4];
    int cols[4];
#pragma unroll
    for (int nb = 0; nb < 4; ++nb) {
        int col = nb * 16 + lrow;
        cols[nb] = col;
        biasc[nb] = bconv[col];
        leftc[nb] = (col < 32) ? left[i * 32 + col] : 0.f;
    }
    const float* prow = pin + ((size_t)i << 16);
    float* orow = pout + ((size_t)i << 16);

    for (int s = 0; s < 16; ++s) {
        int j0 = s * 64 + w * 16;
        int arow = j0 + lrow;
        const float* pr = prow + arow * 64;
        float4 p0 = *(const float4*)(pr + koff);
        float4 p1 = *(const float4*)(pr + koff + 4);
        float4 r0 = *(const float4*)(right + arow * 32 + koff);
        float4 r1 = *(const float4*)(right + arow * 32 + koff + 4);
        float4 p2 = *(const float4*)(pr + 32 + koff);
        float4 p3 = *(const float4*)(pr + 32 + koff + 4);
        bf16x8 A0, A1;
        A0[0] = f2bf(p0.x + lfA[0] + r0.x);
        A0[1] = f2bf(p0.y + lfA[1] + r0.y);
        A0[2] = f2bf(p0.z + lfA[2] + r0.z);
        A0[3] = f2bf(p0.w + lfA[3] + r0.w);
        A0[4] = f2bf(p1.x + lfA[4] + r1.x);
        A0[5] = f2bf(p1.y + lfA[5] + r1.y);
        A0[6] = f2bf(p1.z + lfA[6] + r1.z);
        A0[7] = f2bf(p1.w + lfA[7] + r1.w);
        A1[0] = f2bf(p2.x); A1[1] = f2bf(p2.y); A1[2] = f2bf(p2.z); A1[3] = f2bf(p2.w);
        A1[4] = f2bf(p3.x); A1[5] = f2bf(p3.y); A1[6] = f2bf(p3.z); A1[7] = f2bf(p3.w);

        f32x4 acc[4];
#pragma unroll
        for (int nb = 0; nb < 4; ++nb) {
            acc[nb] = (f32x4){0.f, 0.f, 0.f, 0.f};
            acc[nb] = __builtin_amdgcn_mfma_f32_16x16x32_bf16(A0, Bf[0][nb], acc[nb], 0, 0, 0);
            acc[nb] = __builtin_amdgcn_mfma_f32_16x16x32_bf16(A1, Bf[1][nb], acc[nb], 0, 0, 0);
        }
        // epilogue: C layout col = nb*16 + (l&15), row = j0 + kgrp*4 + q
        int rbase = j0 + kgrp * 4;
#pragma unroll
        for (int nb = 0; nb < 4; ++nb) {
            int col = cols[nb];
#pragma unroll
            for (int q = 0; q < 4; ++q) {
                int row = rbase + q;
                float p = prow[row * 64 + col];
                float pprime = p + ((col < 32) ? (leftc[nb] + right[row * 32 + col]) : 0.f);
                orow[row * 64 + col] = pprime + acc[nb][q] + biasc[nb];
            }
        }
    }
}

// ---------------- IPA: local->global frames + qq/kk ----------------
__global__ __launch_bounds__(256) void to_global_k(const float* __restrict__ qp,
                                                   const float* __restrict__ kp,
                                                   const float* __restrict__ vp,
                                                   const float* __restrict__ R,
                                                   const float* __restrict__ t,
                                                   float* __restrict__ qpg,
                                                   float* __restrict__ kpg,
                                                   float* __restrict__ vpg,
                                                   float* __restrict__ qq,
                                                   float* __restrict__ kk) {
    int i = blockIdx.x, tid = threadIdx.x;
    __shared__ float sR[9], sT[3], sG[96];
    if (tid < 9) sR[tid] = R[i * 9 + tid];
    if (tid < 3) sT[tid] = t[i * 3 + tid];
    __syncthreads();
    if (tid < 144) {
        int tensor = tid / 48, rem = tid % 48;
        int comp = rem % 3, base = rem - comp;
        const float* in = (tensor == 0) ? qp : ((tensor == 1) ? kp : vp);
        float v = sT[comp];
#pragma unroll
        for (int jj = 0; jj < 3; ++jj) v += sR[comp * 3 + jj] * in[i * 48 + base + jj];
        float* outp = (tensor == 0) ? qpg : ((tensor == 1) ? kpg : vpg);
        outp[i * 48 + rem] = v;
        if (tensor < 2) sG[tensor * 48 + rem] = v;
    }
    __syncthreads();
    if (tid < 8) {
        int tensor = tid >> 2, h = tid & 3;
        float s = 0.f;
#pragma unroll
        for (int e = 0; e < 12; ++e) {
            float v = sG[tensor * 48 + h * 12 + e];
            s += v * v;
        }
        (tensor == 0 ? qq : kk)[i * 4 + h] = s;
    }
}

// ---------------- IPA attention: one block per (i,h) ----------------
__global__ __launch_bounds__(256) void ipa_attn_k(const float* __restrict__ q,
                                                  const float* __restrict__ k,
                                                  const float* __restrict__ v,
                                                  const float* __restrict__ qpg,
                                                  const float* __restrict__ kpg,
                                                  const float* __restrict__ vpg,
                                                  const float* __restrict__ qq,
                                                  const float* __restrict__ kk,
                                                  const float* __restrict__ headw,
                                                  float* __restrict__ feat,
                                                  float* __restrict__ optg) {
    int i = blockIdx.x >> 2, h = blockIdx.x & 3;
    __shared__ float s_q[32], s_qp[12], s_p[NSEQ], s_r[256], sw[8], s_sc[2];
    int tid = threadIdx.x;
    if (tid < 32) s_q[tid] = q[i * 128 + h * 32 + tid];
    if (tid < 12) s_qp[tid] = qpg[i * 48 + h * 12 + tid];
    if (tid == 0) {
        s_sc[0] = qq[i * 4 + h];
        float gamma = log1pf(__expf(headw[h]));  // softplus
        s_sc[1] = gamma * 0.23570226039f * 0.5f;  // gamma * wC * 0.5, wC=sqrt(1/18)
    }
    __syncthreads();
    float qqv = s_sc[0], coef = s_sc[1];
    float lv[4];
    float lmax = -1e30f;
#pragma unroll
    for (int it = 0; it < 4; ++it) {
        int j = tid + it * 256;
        const float4* kj = (const float4*)(k + j * 128 + h * 32);
        float dot = 0.f;
#pragma unroll
        for (int c4 = 0; c4 < 8; ++c4) {
            float4 kvv = kj[c4];
            dot += s_q[c4 * 4 + 0] * kvv.x + s_q[c4 * 4 + 1] * kvv.y +
                   s_q[c4 * 4 + 2] * kvv.z + s_q[c4 * 4 + 3] * kvv.w;
        }
        float scalar = dot * 0.17677669529f;
        const float* kpj = kpg + j * 48 + h * 12;
        float d12 = 0.f;
#pragma unroll
        for (int e = 0; e < 12; ++e) d12 += s_qp[e] * kpj[e];
        float d2 = qqv + kk[j * 4 + h] - 2.f * d12;
        float l = 0.70710678118f * (scalar - coef * d2);
        lv[it] = l;
        lmax = fmaxf(lmax, l);
    }
    lmax = block_reduce_max(lmax, sw);
    float lsum = 0.f;
#pragma unroll
    for (int it = 0; it < 4; ++it) {
        float e = __expf(lv[it] - lmax);
        s_p[tid + it * 256] = e;
        lsum += e;
    }
    lsum = block_reduce_sum(lsum, sw);
    float inv = 1.f / lsum;
    // o part (32 channels)
    int c = tid & 31, g = tid >> 5;
    float acc = 0.f;
    const float* vbase = v + h * 32 + c;
    for (int j = g * 128; j < g * 128 + 128; ++j) acc += s_p[j] * vbase[j * 128];
    s_r[tid] = acc;
    __syncthreads();
    if (tid < 32) {
        float s = 0.f;
#pragma unroll
        for (int gg = 0; gg < 8; ++gg) s += s_r[gg * 32 + tid];
        feat[i * 192 + h * 32 + tid] = s * inv;
    }
    // opt part (12 dims, global frame)
    __syncthreads();
    int e2 = tid & 15, g2 = tid >> 4;
    float acc2 = 0.f;
    if (e2 < 12) {
        const float* vpb = vpg + h * 12 + e2;
        for (int j = g2 * 64; j < g2 * 64 + 64; ++j) acc2 += s_p[j] * vpb[j * 48];
    }
    s_r[tid] = acc2;
    __syncthreads();
    if (tid < 12) {
        float s = 0.f;
#pragma unroll
        for (int gg = 0; gg < 16; ++gg) s += s_r[gg * 16 + tid];
        optg[i * 48 + h * 12 + tid] = s * inv;
    }
}

// ---------------- opt -> local frame + norms -> feat tail ----------------
__global__ __launch_bounds__(64) void feat_finish_k(const float* __restrict__ optg,
                                                    const float* __restrict__ R,
                                                    const float* __restrict__ t,
                                                    float* __restrict__ feat) {
    int i = blockIdx.x, tid = threadIdx.x;
    __shared__ float sR[9], sT[3], sL[48];
    if (tid < 9) sR[tid] = R[i * 9 + tid];
    if (tid < 3) sT[tid] = t[i * 3 + tid];
    __syncthreads();
    if (tid < 48) {
        int comp = tid % 3, base = tid - comp;
        float v = 0.f;
#pragma unroll
        for (int jj = 0; jj < 3; ++jj)
            v += sR[jj * 3 + comp] * (optg[i * 48 + base + jj] - sT[jj]);
        sL[tid] = v;
        feat[i * 192 + 128 + tid] = v;
    }
    __syncthreads();
    if (tid < 16) {
        float s = 1e-8f;
#pragma unroll
        for (int comp = 0; comp < 3; ++comp) {
            float v = sL[tid * 3 + comp];
            s += v * v;
        }
        feat[i * 192 + 176 + tid] = sqrtf(s);
    }
}

// ---------------- frames pass-through ----------------
__global__ __launch_bounds__(256) void copy_frames_k(const float* __restrict__ R,
                                                     const float* __restrict__ t,
                                                     float* __restrict__ out) {
    int idx = blockIdx.x * 256 + threadIdx.x;
    if (idx < 9216) out[idx] = R[idx];
    else if (idx < 12288) out[idx] = t[idx - 9216];
}

extern "C" void kernel_launch(void* const* d_in, const int* in_sizes, int n_in,
                              void* d_out, int out_size, void* d_ws, size_t ws_size,
                              hipStream_t stream) {
    const float* seq    = (const float*)d_in[0];
    const float* pair   = (const float*)d_in[1];
    const float* fR     = (const float*)d_in[2];
    const float* ft     = (const float*)d_in[3];
    const float* ln1g   = (const float*)d_in[4];
    const float* ln1b   = (const float*)d_in[5];
    const float* w_qkv  = (const float*)d_in[6];
    const float* b_qkv  = (const float*)d_in[7];
    const float* w_o    = (const float*)d_in[8];
    const float* b_o    = (const float*)d_in[9];
    const float* w_2to1 = (const float*)d_in[10];
    const float* b_2to1 = (const float*)d_in[11];
    const float* lnffg  = (const float*)d_in[12];
    const float* lnffb  = (const float*)d_in[13];
    const float* w_ff1  = (const float*)d_in[14];
    const float* b_ff1  = (const float*)d_in[15];
    const float* w_ff2  = (const float*)d_in[16];
    const float* b_ff2  = (const float*)d_in[17];
    const float* w_l    = (const float*)d_in[18];
    const float* b_l    = (const float*)d_in[19];
    const float* w_r    = (const float*)d_in[20];
    const float* b_r    = (const float*)d_in[21];
    const float* w_conv = (const float*)d_in[22];
    const float* b_conv = (const float*)d_in[23];
    const float* wq     = (const float*)d_in[24];
    const float* wk     = (const float*)d_in[25];
    const float* wv     = (const float*)d_in[26];
    const float* wqp    = (const float*)d_in[27];
    const float* wkp    = (const float*)d_in[28];
    const float* wvp    = (const float*)d_in[29];
    const float* headw  = (const float*)d_in[30];
    const float* wout   = (const float*)d_in[31];
    const float* bout   = (const float*)d_in[32];
    const float* ln3g   = (const float*)d_in[33];
    const float* ln3b   = (const float*)d_in[34];

    float* ws = (float*)d_ws;
    float* xn      = ws; ws += 131072;
    float* qkvb    = ws; ws += 393216;
    float* abuf    = ws; ws += 131072;
    float* x1      = ws; ws += 131072;
    float* x2      = ws; ws += 131072;
    float* hdn     = ws; ws += 131072;
    float* ff1     = ws; ws += 524288;
    float* xa      = ws; ws += 131072;
    float* pmean   = ws; ws += 65536;
    float* left    = ws; ws += 32768;
    float* right   = ws; ws += 32768;
    float* qb      = ws; ws += 131072;
    float* kb      = ws; ws += 131072;
    float* vb      = ws; ws += 131072;
    float* qp      = ws; ws += 49152;
    float* kp      = ws; ws += 49152;
    float* vp      = ws; ws += 49152;
    float* qpg     = ws; ws += 49152;
    float* kpg     = ws; ws += 49152;
    float* vpg     = ws; ws += 49152;
    float* qqb     = ws; ws += 4096;
    float* kkb     = ws; ws += 4096;
    float* feat    = ws; ws += 196608;
    float* optg    = ws; ws += 49152;
    float* ipa_out = ws; ws += 131072;

    float* out_x    = (float*)d_out;
    float* out_pair = out_x + 131072;
    float* out_R    = out_pair + 67108864;
    float* out_t    = out_R + 9216;

    const int N = NSEQ;

    // pair mean over j (biggest single read; launch first)
    pair_mean_k<<<N, 256, 0, stream>>>(pair, pmean);

    // 1D track: pre-LN MHA
    ln128_k<<<N, 128, 0, stream>>>(seq, ln1g, ln1b, nullptr, xn);
    gemm_rows_k<128, 384, 0><<<N / 4, 256, 0, stream>>>(xn, w_qkv, b_qkv, nullptr, qkvb);
    mha_attn_k<<<N * NH, 256, 0, stream>>>(qkvb, abuf);
    gemm_rows_k<128, 128, 0><<<N / 4, 256, 0, stream>>>(abuf, w_o, b_o, seq, x1);

    // pair -> 1D aggregation
    gemm_rows_k<64, 128, 0><<<N / 4, 256, 0, stream>>>(pmean, w_2to1, b_2to1, x1, x2);

    // FFN
    ln128_k<<<N, 128, 0, stream>>>(x2, lnffg, lnffb, nullptr, hdn);
    gemm_rows_k<128, 512, 1><<<N / 4, 256, 0, stream>>>(hdn, w_ff1, b_ff1, nullptr, ff1);
    gemm_rows_k<512, 128, 0><<<N / 4, 256, 0, stream>>>(ff1, w_ff2, b_ff2, x2, xa);

    // fused projections: q,k,v,qp,kp,vp,left,right (all from xa)
    proj_all_k<<<N / 4, 256, 0, stream>>>(xa, wq, wk, wv, wqp, wkp, wvp,
                                          w_l, b_l, w_r, b_r,
                                          qb, kb, vb, qp, kp, vp, left, right);

    // pair outer + 1x1 conv via bf16 MFMA (single pass over pair)
    pair_update_mfma_k<<<N, 256, 0, stream>>>(pair, left, right, w_conv, b_conv, out_pair);

    // frames to global + squared sums
    to_global_k<<<N, 256, 0, stream>>>(qp, kp, vp, fR, ft, qpg, kpg, vpg, qqb, kkb);

    // IPA attention
    ipa_attn_k<<<N * NH, 256, 0, stream>>>(qb, kb, vb, qpg, kpg, vpg, qqb, kkb, headw,
                                           feat, optg);

    // local frame + norms -> feat tail
    feat_finish_k<<<N, 64, 0, stream>>>(optg, fR, ft, feat);

    // IPA output projection
    gemm_rows_k<192, 128, 0><<<N / 4, 256, 0, stream>>>(feat, wout, bout, nullptr, ipa_out);

    // final residual + post-LN
    ln128_k<<<N, 128, 0, stream>>>(ipa_out, ln3g, ln3b, xa, out_x);

    // frames pass-through
    copy_frames_k<<<48, 256, 0, stream>>>(fR, ft, out_t - 9216);
}

// Round 7
// 1049.559 us; speedup vs baseline: 1.3842x; 1.1268x over previous
//
#include <hip/hip_runtime.h>
#include <math.h>

// Problem constants
#define NSEQ 1024
#define D1C 128
#define D2C 64
#define NH 4
#define CH 32

typedef __attribute__((ext_vector_type(8))) short bf16x8;
typedef __attribute__((ext_vector_type(4))) float f32x4;

__device__ __forceinline__ short f2bf(float f) {
    unsigned u = __float_as_uint(f);
    unsigned r = (u + 0x7fffu + ((u >> 16) & 1u)) >> 16;  // RNE
    return (short)r;
}

// ---------------- reduction helpers ----------------
__device__ __forceinline__ float block_reduce_sum(float v, float* s) {
    __syncthreads();
    int lane = threadIdx.x & 63, wid = threadIdx.x >> 6;
#pragma unroll
    for (int off = 32; off > 0; off >>= 1) v += __shfl_down(v, off, 64);
    if (lane == 0) s[wid] = v;
    __syncthreads();
    float t = 0.f;
    int nw = (blockDim.x + 63) >> 6;
    for (int w = 0; w < nw; ++w) t += s[w];
    return t;
}

__device__ __forceinline__ float block_reduce_max(float v, float* s) {
    __syncthreads();
    int lane = threadIdx.x & 63, wid = threadIdx.x >> 6;
#pragma unroll
    for (int off = 32; off > 0; off >>= 1) v = fmaxf(v, __shfl_down(v, off, 64));
    if (lane == 0) s[wid] = v;
    __syncthreads();
    float t = -1e30f;
    int nw = (blockDim.x + 63) >> 6;
    for (int w = 0; w < nw; ++w) t = fmaxf(t, s[w]);
    return t;
}

// ---------------- pair mean over j ----------------
__global__ __launch_bounds__(256) void pair_mean_k(const float* __restrict__ pin,
                                                   float* __restrict__ pmean) {
    int i = blockIdx.x;
    int c4 = threadIdx.x & 15;
    int g  = threadIdx.x >> 4;
    const float4* p4 = (const float4*)(pin + ((size_t)i << 16));
    float4 acc = {0.f, 0.f, 0.f, 0.f};
    for (int j = g; j < NSEQ; j += 16) {
        float4 v = p4[j * 16 + c4];
        acc.x += v.x; acc.y += v.y; acc.z += v.z; acc.w += v.w;
    }
    __shared__ float4 s[256];
    s[threadIdx.x] = acc;
    __syncthreads();
    if (threadIdx.x < 16) {
        float4 t = {0.f, 0.f, 0.f, 0.f};
        for (int gg = 0; gg < 16; ++gg) {
            float4 v = s[gg * 16 + threadIdx.x];
            t.x += v.x; t.y += v.y; t.z += v.z; t.w += v.w;
        }
        const float inv = 1.f / 1024.f;
        t.x *= inv; t.y *= inv; t.z *= inv; t.w *= inv;
        ((float4*)(pmean + i * 64))[threadIdx.x] = t;
    }
}

// ---------------- LayerNorm over 128 channels (optional residual add) ----------------
__global__ __launch_bounds__(128) void ln128_k(const float* __restrict__ x,
                                               const float* __restrict__ g,
                                               const float* __restrict__ b,
                                               const float* __restrict__ res,
                                               float* __restrict__ out) {
    __shared__ float sw[4];
    int i = blockIdx.x, tid = threadIdx.x;
    float v = x[i * D1C + tid];
    float m = block_reduce_sum(v, sw) * (1.f / 128.f);
    float d = v - m;
    float var = block_reduce_sum(d * d, sw) * (1.f / 128.f);
    float y = d * rsqrtf(var + 1e-5f) * g[tid] + b[tid];
    if (res) y += res[i * D1C + tid];
    out[i * D1C + tid] = y;
}

// ---------------- row-block GEMM ----------------
template <int K, int NOUT, int ACT>  // ACT: 0=none, 1=exact gelu
__global__ __launch_bounds__(256) void gemm_rows_k(const float* __restrict__ in,
                                                   const float* __restrict__ W,
                                                   const float* __restrict__ bias,
                                                   const float* __restrict__ res,
                                                   float* __restrict__ out) {
    int row0 = blockIdx.x * 4;
    __shared__ float s_in[4][K];
    for (int idx = threadIdx.x; idx < 4 * K; idx += 256) {
        int r = idx / K, k = idx % K;
        s_in[r][k] = in[(row0 + r) * K + k];
    }
    __syncthreads();
    for (int o = threadIdx.x; o < NOUT; o += 256) {
        float a0 = 0.f, a1 = 0.f, a2 = 0.f, a3 = 0.f;
#pragma unroll 4
        for (int k = 0; k < K; ++k) {
            float w = W[k * NOUT + o];
            a0 += s_in[0][k] * w;
            a1 += s_in[1][k] * w;
            a2 += s_in[2][k] * w;
            a3 += s_in[3][k] * w;
        }
        float accs[4] = {a0, a1, a2, a3};
        float bb = bias ? bias[o] : 0.f;
#pragma unroll
        for (int r = 0; r < 4; ++r) {
            float v = accs[r] + bb;
            if (ACT == 1) v = 0.5f * v * (1.f + erff(v * 0.70710678118f));
            if (res) v += res[(row0 + r) * NOUT + o];
            out[(row0 + r) * NOUT + o] = v;
        }
    }
}

// ---------------- tiled transpose: out[c][j] = in[j*LD + OFF + c] ----------------
template <int LD, int OFF>
__global__ __launch_bounds__(256) void transposeK_k(const float* __restrict__ in,
                                                    float* __restrict__ out) {
    __shared__ float tile[32][33];
    int jt = blockIdx.x * 32, ct = blockIdx.y * 32;
    int c = threadIdx.x & 31, r = threadIdx.x >> 5;  // r = 0..7
    for (int rr = r; rr < 32; rr += 8)
        tile[rr][c] = in[(size_t)(jt + rr) * LD + OFF + ct + c];
    __syncthreads();
    for (int rr = r; rr < 32; rr += 8)
        out[(size_t)(ct + rr) * NSEQ + jt + c] = tile[c][rr];
}

// ---------------- fused projections from xa (also emits kTi transposed) ----------------
__global__ __launch_bounds__(256) void proj_all_k(
    const float* __restrict__ xa,
    const float* __restrict__ wq, const float* __restrict__ wk, const float* __restrict__ wv,
    const float* __restrict__ wqp, const float* __restrict__ wkp, const float* __restrict__ wvp,
    const float* __restrict__ w_l, const float* __restrict__ b_l,
    const float* __restrict__ w_r, const float* __restrict__ b_r,
    float* __restrict__ qb, float* __restrict__ kb, float* __restrict__ vb,
    float* __restrict__ qp, float* __restrict__ kp, float* __restrict__ vp,
    float* __restrict__ left, float* __restrict__ right,
    float* __restrict__ kTi) {
    int row0 = blockIdx.x * 4;
    __shared__ float s_in[4][128];
    for (int idx = threadIdx.x; idx < 512; idx += 256)
        s_in[idx >> 7][idx & 127] = xa[row0 * 128 + idx];
    __syncthreads();
    for (int o = threadIdx.x; o < 592; o += 256) {
        const float* W; float* dst; int no, oc; float bb = 0.f; int isk = 0;
        if (o < 384) {
            int sel = o >> 7; oc = o & 127; no = 128;
            W = sel == 0 ? wq : (sel == 1 ? wk : wv);
            dst = sel == 0 ? qb : (sel == 1 ? kb : vb);
            isk = (sel == 1);
        } else if (o < 528) {
            int r = o - 384; int sel = r / 48; oc = r % 48; no = 48;
            W = sel == 0 ? wqp : (sel == 1 ? wkp : wvp);
            dst = sel == 0 ? qp : (sel == 1 ? kp : vp);
        } else if (o < 560) {
            oc = o - 528; no = 32; W = w_l; dst = left; bb = b_l[oc];
        } else {
            oc = o - 560; no = 32; W = w_r; dst = right; bb = b_r[oc];
        }
        float a0 = 0.f, a1 = 0.f, a2 = 0.f, a3 = 0.f;
#pragma unroll 4
        for (int k = 0; k < 128; ++k) {
            float w = W[k * no + oc];
            a0 += s_in[0][k] * w;
            a1 += s_in[1][k] * w;
            a2 += s_in[2][k] * w;
            a3 += s_in[3][k] * w;
        }
        dst[(row0 + 0) * no + oc] = a0 + bb;
        dst[(row0 + 1) * no + oc] = a1 + bb;
        dst[(row0 + 2) * no + oc] = a2 + bb;
        dst[(row0 + 3) * no + oc] = a3 + bb;
        if (isk) {
            float4 t = {a0, a1, a2, a3};
            *(float4*)(kTi + (size_t)oc * NSEQ + row0) = t;
        }
    }
}

// ---------------- MHA attention: one block per (i,h), K read transposed ----------------
__global__ __launch_bounds__(256) void mha_attn_k(const float* __restrict__ qkv,
                                                  const float* __restrict__ kTm,
                                                  float* __restrict__ aout) {
    int i = blockIdx.x >> 2, h = blockIdx.x & 3;
    __shared__ float s_q[32];
    __shared__ float s_p[NSEQ];
    __shared__ float s_r[256];
    __shared__ float sw[8];
    int tid = threadIdx.x;
    if (tid < 32) s_q[tid] = qkv[i * 384 + h * 32 + tid];
    __syncthreads();
    float lv[4];
    float lmax = -1e30f;
#pragma unroll
    for (int it = 0; it < 2; ++it) {
        int j = 2 * tid + it * 512;
        float d0 = 0.f, d1 = 0.f;
#pragma unroll
        for (int c = 0; c < 32; ++c) {
            float2 kv = *(const float2*)(kTm + (size_t)(h * 32 + c) * NSEQ + j);
            d0 += s_q[c] * kv.x;
            d1 += s_q[c] * kv.y;
        }
        float l0 = d0 * 0.17677669529f;
        float l1 = d1 * 0.17677669529f;
        lv[2 * it] = l0; lv[2 * it + 1] = l1;
        lmax = fmaxf(lmax, fmaxf(l0, l1));
    }
    lmax = block_reduce_max(lmax, sw);
    float lsum = 0.f;
#pragma unroll
    for (int it = 0; it < 2; ++it) {
        int j = 2 * tid + it * 512;
        float e0 = __expf(lv[2 * it] - lmax);
        float e1 = __expf(lv[2 * it + 1] - lmax);
        ((float2*)s_p)[j >> 1] = (float2){e0, e1};
        lsum += e0 + e1;
    }
    lsum = block_reduce_sum(lsum, sw);  // also makes s_p visible
    float inv = 1.f / lsum;
    int c = tid & 31, g = tid >> 5;
    float acc = 0.f;
    const float* vbase = qkv + 256 + h * 32 + c;
    for (int j = g * 128; j < g * 128 + 128; ++j) acc += s_p[j] * vbase[j * 384];
    s_r[tid] = acc;
    __syncthreads();
    if (tid < 32) {
        float s = 0.f;
#pragma unroll
        for (int gg = 0; gg < 8; ++gg) s += s_r[gg * 32 + tid];
        aout[i * 128 + h * 32 + tid] = s * inv;
    }
}

// ---------------- pair update via MFMA ----------------
__global__ __launch_bounds__(256) void pair_update_mfma_k(
    const float* __restrict__ pin,
    const float* __restrict__ left,    // [N][32]
    const float* __restrict__ right,   // [N][32]
    const float* __restrict__ wconv,   // [64][64]
    const float* __restrict__ bconv,   // [64]
    float* __restrict__ pout) {
    int i = blockIdx.x;
    int tid = threadIdx.x;
    int w = tid >> 6;
    int l = tid & 63;
    int lrow = l & 15;
    int kgrp = l >> 4;
    int koff = kgrp * 8;

    bf16x8 Bf[2][4];
#pragma unroll
    for (int kh = 0; kh < 2; ++kh)
#pragma unroll
        for (int nb = 0; nb < 4; ++nb) {
            int col = nb * 16 + lrow;
            bf16x8 bf;
#pragma unroll
            for (int e = 0; e < 8; ++e)
                bf[e] = f2bf(wconv[(kh * 32 + koff + e) * 64 + col]);
            Bf[kh][nb] = bf;
        }
    float lfA[8];
    {
        float4 l0 = *(const float4*)(left + i * 32 + koff);
        float4 l1 = *(const float4*)(left + i * 32 + koff + 4);
        lfA[0] = l0.x; lfA[1] = l0.y; lfA[2] = l0.z; lfA[3] = l0.w;
        lfA[4] = l1.x; lfA[5] = l1.y; lfA[6] = l1.z; lfA[7] = l1.w;
    }
    float biasc[4], leftc[4];
    int cols[4];
#pragma unroll
    for (int nb = 0; nb < 4; ++nb) {
        int col = nb * 16 + lrow;
        cols[nb] = col;
        biasc[nb] = bconv[col];
        leftc[nb] = (col < 32) ? left[i * 32 + col] : 0.f;
    }
    const float* prow = pin + ((size_t)i << 16);
    float* orow = pout + ((size_t)i << 16);

    for (int s = 0; s < 16; ++s) {
        int j0 = s * 64 + w * 16;
        int arow = j0 + lrow;
        const float* pr = prow + arow * 64;
        float4 p0 = *(const float4*)(pr + koff);
        float4 p1 = *(const float4*)(pr + koff + 4);
        float4 r0 = *(const float4*)(right + arow * 32 + koff);
        float4 r1 = *(const float4*)(right + arow * 32 + koff + 4);
        float4 p2 = *(const float4*)(pr + 32 + koff);
        float4 p3 = *(const float4*)(pr + 32 + koff + 4);
        bf16x8 A0, A1;
        A0[0] = f2bf(p0.x + lfA[0] + r0.x);
        A0[1] = f2bf(p0.y + lfA[1] + r0.y);
        A0[2] = f2bf(p0.z + lfA[2] + r0.z);
        A0[3] = f2bf(p0.w + lfA[3] + r0.w);
        A0[4] = f2bf(p1.x + lfA[4] + r1.x);
        A0[5] = f2bf(p1.y + lfA[5] + r1.y);
        A0[6] = f2bf(p1.z + lfA[6] + r1.z);
        A0[7] = f2bf(p1.w + lfA[7] + r1.w);
        A1[0] = f2bf(p2.x); A1[1] = f2bf(p2.y); A1[2] = f2bf(p2.z); A1[3] = f2bf(p2.w);
        A1[4] = f2bf(p3.x); A1[5] = f2bf(p3.y); A1[6] = f2bf(p3.z); A1[7] = f2bf(p3.w);

        f32x4 acc[4];
#pragma unroll
        for (int nb = 0; nb < 4; ++nb) {
            acc[nb] = (f32x4){0.f, 0.f, 0.f, 0.f};
            acc[nb] = __builtin_amdgcn_mfma_f32_16x16x32_bf16(A0, Bf[0][nb], acc[nb], 0, 0, 0);
            acc[nb] = __builtin_amdgcn_mfma_f32_16x16x32_bf16(A1, Bf[1][nb], acc[nb], 0, 0, 0);
        }
        int rbase = j0 + kgrp * 4;
#pragma unroll
        for (int nb = 0; nb < 4; ++nb) {
            int col = cols[nb];
#pragma unroll
            for (int q = 0; q < 4; ++q) {
                int row = rbase + q;
                float p = prow[row * 64 + col];
                float pprime = p + ((col < 32) ? (leftc[nb] + right[row * 32 + col]) : 0.f);
                orow[row * 64 + col] = pprime + acc[nb][q] + biasc[nb];
            }
        }
    }
}

// ---------------- IPA: local->global frames + qq/kk (+ transposed kpgT, kkT) ----------------
__global__ __launch_bounds__(256) void to_global_k(const float* __restrict__ qp,
                                                   const float* __restrict__ kp,
                                                   const float* __restrict__ vp,
                                                   const float* __restrict__ R,
                                                   const float* __restrict__ t,
                                                   float* __restrict__ qpg,
                                                   float* __restrict__ kpgT,  // [48][N]
                                                   float* __restrict__ vpg,
                                                   float* __restrict__ qq,
                                                   float* __restrict__ kkT) { // [4][N]
    int i = blockIdx.x, tid = threadIdx.x;
    __shared__ float sR[9], sT[3], sG[96];
    if (tid < 9) sR[tid] = R[i * 9 + tid];
    if (tid < 3) sT[tid] = t[i * 3 + tid];
    __syncthreads();
    if (tid < 144) {
        int tensor = tid / 48, rem = tid % 48;
        int comp = rem % 3, base = rem - comp;
        const float* in = (tensor == 0) ? qp : ((tensor == 1) ? kp : vp);
        float v = sT[comp];
#pragma unroll
        for (int jj = 0; jj < 3; ++jj) v += sR[comp * 3 + jj] * in[i * 48 + base + jj];
        if (tensor == 0) qpg[i * 48 + rem] = v;
        else if (tensor == 1) kpgT[rem * NSEQ + i] = v;
        else vpg[i * 48 + rem] = v;
        if (tensor < 2) sG[tensor * 48 + rem] = v;
    }
    __syncthreads();
    if (tid < 8) {
        int tensor = tid >> 2, h = tid & 3;
        float s = 0.f;
#pragma unroll
        for (int e = 0; e < 12; ++e) {
            float v = sG[tensor * 48 + h * 12 + e];
            s += v * v;
        }
        if (tensor == 0) qq[i * 4 + h] = s;
        else kkT[h * NSEQ + i] = s;
    }
}

// ---------------- IPA attention: one block per (i,h), K/kp/kk read transposed ----------------
__global__ __launch_bounds__(256) void ipa_attn_k(const float* __restrict__ q,
                                                  const float* __restrict__ v,
                                                  const float* __restrict__ kTi,
                                                  const float* __restrict__ kpgT,
                                                  const float* __restrict__ kkT,
                                                  const float* __restrict__ qpg,
                                                  const float* __restrict__ vpg,
                                                  const float* __restrict__ qq,
                                                  const float* __restrict__ headw,
                                                  float* __restrict__ feat,
                                                  float* __restrict__ optg) {
    int i = blockIdx.x >> 2, h = blockIdx.x & 3;
    __shared__ float s_q[32], s_qp[12], s_p[NSEQ], s_r[256], sw[8], s_sc[2];
    int tid = threadIdx.x;
    if (tid < 32) s_q[tid] = q[i * 128 + h * 32 + tid];
    if (tid < 12) s_qp[tid] = qpg[i * 48 + h * 12 + tid];
    if (tid == 0) {
        s_sc[0] = qq[i * 4 + h];
        float gamma = log1pf(__expf(headw[h]));  // softplus
        s_sc[1] = gamma * 0.23570226039f * 0.5f;  // gamma * wC * 0.5, wC=sqrt(1/18)
    }
    __syncthreads();
    float qqv = s_sc[0], coef = s_sc[1];
    float lv[4];
    float lmax = -1e30f;
#pragma unroll
    for (int it = 0; it < 2; ++it) {
        int j = 2 * tid + it * 512;
        float d0 = 0.f, d1 = 0.f;
#pragma unroll
        for (int c = 0; c < 32; ++c) {
            float2 kv = *(const float2*)(kTi + (size_t)(h * 32 + c) * NSEQ + j);
            d0 += s_q[c] * kv.x;
            d1 += s_q[c] * kv.y;
        }
        float p0 = 0.f, p1 = 0.f;
#pragma unroll
        for (int e = 0; e < 12; ++e) {
            float2 kv = *(const float2*)(kpgT + (size_t)(h * 12 + e) * NSEQ + j);
            p0 += s_qp[e] * kv.x;
            p1 += s_qp[e] * kv.y;
        }
        float2 kkv = *(const float2*)(kkT + (size_t)h * NSEQ + j);
        float l0 = 0.70710678118f * (d0 * 0.17677669529f - coef * (qqv + kkv.x - 2.f * p0));
        float l1 = 0.70710678118f * (d1 * 0.17677669529f - coef * (qqv + kkv.y - 2.f * p1));
        lv[2 * it] = l0; lv[2 * it + 1] = l1;
        lmax = fmaxf(lmax, fmaxf(l0, l1));
    }
    lmax = block_reduce_max(lmax, sw);
    float lsum = 0.f;
#pragma unroll
    for (int it = 0; it < 2; ++it) {
        int j = 2 * tid + it * 512;
        float e0 = __expf(lv[2 * it] - lmax);
        float e1 = __expf(lv[2 * it + 1] - lmax);
        ((float2*)s_p)[j >> 1] = (float2){e0, e1};
        lsum += e0 + e1;
    }
    lsum = block_reduce_sum(lsum, sw);
    float inv = 1.f / lsum;
    // o part (32 channels)
    int c = tid & 31, g = tid >> 5;
    float acc = 0.f;
    const float* vbase = v + h * 32 + c;
    for (int j = g * 128; j < g * 128 + 128; ++j) acc += s_p[j] * vbase[j * 128];
    s_r[tid] = acc;
    __syncthreads();
    if (tid < 32) {
        float s = 0.f;
#pragma unroll
        for (int gg = 0; gg < 8; ++gg) s += s_r[gg * 32 + tid];
        feat[i * 192 + h * 32 + tid] = s * inv;
    }
    // opt part (12 dims, global frame); j strided by 16 to avoid same-bank broadcast
    __syncthreads();
    int e2 = tid & 15, g2 = tid >> 4;
    float acc2 = 0.f;
    if (e2 < 12) {
        const float* vpb = vpg + h * 12 + e2;
        for (int jj = 0; jj < 64; ++jj) {
            int j = g2 + (jj << 4);
            acc2 += s_p[j] * vpb[j * 48];
        }
    }
    s_r[tid] = acc2;
    __syncthreads();
    if (tid < 12) {
        float s = 0.f;
#pragma unroll
        for (int gg = 0; gg < 16; ++gg) s += s_r[gg * 16 + tid];
        optg[i * 48 + h * 12 + tid] = s * inv;
    }
}

// ---------------- opt -> local frame + norms -> feat tail ----------------
__global__ __launch_bounds__(64) void feat_finish_k(const float* __restrict__ optg,
                                                    const float* __restrict__ R,
                                                    const float* __restrict__ t,
                                                    float* __restrict__ feat) {
    int i = blockIdx.x, tid = threadIdx.x;
    __shared__ float sR[9], sT[3], sL[48];
    if (tid < 9) sR[tid] = R[i * 9 + tid];
    if (tid < 3) sT[tid] = t[i * 3 + tid];
    __syncthreads();
    if (tid < 48) {
        int comp = tid % 3, base = tid - comp;
        float v = 0.f;
#pragma unroll
        for (int jj = 0; jj < 3; ++jj)
            v += sR[jj * 3 + comp] * (optg[i * 48 + base + jj] - sT[jj]);
        sL[tid] = v;
        feat[i * 192 + 128 + tid] = v;
    }
    __syncthreads();
    if (tid < 16) {
        float s = 1e-8f;
#pragma unroll
        for (int comp = 0; comp < 3; ++comp) {
            float v = sL[tid * 3 + comp];
            s += v * v;
        }
        feat[i * 192 + 176 + tid] = sqrtf(s);
    }
}

// ---------------- frames pass-through ----------------
__global__ __launch_bounds__(256) void copy_frames_k(const float* __restrict__ R,
                                                     const float* __restrict__ t,
                                                     float* __restrict__ out) {
    int idx = blockIdx.x * 256 + threadIdx.x;
    if (idx < 9216) out[idx] = R[idx];
    else if (idx < 12288) out[idx] = t[idx - 9216];
}

extern "C" void kernel_launch(void* const* d_in, const int* in_sizes, int n_in,
                              void* d_out, int out_size, void* d_ws, size_t ws_size,
                              hipStream_t stream) {
    const float* seq    = (const float*)d_in[0];
    const float* pair   = (const float*)d_in[1];
    const float* fR     = (const float*)d_in[2];
    const float* ft     = (const float*)d_in[3];
    const float* ln1g   = (const float*)d_in[4];
    const float* ln1b   = (const float*)d_in[5];
    const float* w_qkv  = (const float*)d_in[6];
    const float* b_qkv  = (const float*)d_in[7];
    const float* w_o    = (const float*)d_in[8];
    const float* b_o    = (const float*)d_in[9];
    const float* w_2to1 = (const float*)d_in[10];
    const float* b_2to1 = (const float*)d_in[11];
    const float* lnffg  = (const float*)d_in[12];
    const float* lnffb  = (const float*)d_in[13];
    const float* w_ff1  = (const float*)d_in[14];
    const float* b_ff1  = (const float*)d_in[15];
    const float* w_ff2  = (const float*)d_in[16];
    const float* b_ff2  = (const float*)d_in[17];
    const float* w_l    = (const float*)d_in[18];
    const float* b_l    = (const float*)d_in[19];
    const float* w_r    = (const float*)d_in[20];
    const float* b_r    = (const float*)d_in[21];
    const float* w_conv = (const float*)d_in[22];
    const float* b_conv = (const float*)d_in[23];
    const float* wq     = (const float*)d_in[24];
    const float* wk     = (const float*)d_in[25];
    const float* wv     = (const float*)d_in[26];
    const float* wqp    = (const float*)d_in[27];
    const float* wkp    = (const float*)d_in[28];
    const float* wvp    = (const float*)d_in[29];
    const float* headw  = (const float*)d_in[30];
    const float* wout   = (const float*)d_in[31];
    const float* bout   = (const float*)d_in[32];
    const float* ln3g   = (const float*)d_in[33];
    const float* ln3b   = (const float*)d_in[34];

    float* ws = (float*)d_ws;
    float* xn      = ws; ws += 131072;
    float* qkvb    = ws; ws += 393216;
    float* abuf    = ws; ws += 131072;
    float* x1      = ws; ws += 131072;
    float* x2      = ws; ws += 131072;
    float* hdn     = ws; ws += 131072;
    float* ff1     = ws; ws += 524288;
    float* xa      = ws; ws += 131072;
    float* pmean   = ws; ws += 65536;
    float* left    = ws; ws += 32768;
    float* right   = ws; ws += 32768;
    float* qb      = ws; ws += 131072;
    float* kb      = ws; ws += 131072;
    float* vb      = ws; ws += 131072;
    float* qp      = ws; ws += 49152;
    float* kp      = ws; ws += 49152;
    float* vp      = ws; ws += 49152;
    float* qpg     = ws; ws += 49152;
    float* vpg     = ws; ws += 49152;
    float* qqb     = ws; ws += 4096;
    float* feat    = ws; ws += 196608;
    float* optg    = ws; ws += 49152;
    float* ipa_out = ws; ws += 131072;
    float* kTm     = ws; ws += 131072;  // [128][1024] MHA K^T
    float* kTi     = ws; ws += 131072;  // [128][1024] IPA K^T
    float* kpgT    = ws; ws += 49152;   // [48][1024]
    float* kkT     = ws; ws += 4096;    // [4][1024]

    float* out_x    = (float*)d_out;
    float* out_pair = out_x + 131072;
    float* out_R    = out_pair + 67108864;
    float* out_t    = out_R + 9216;

    const int N = NSEQ;

    // pair mean over j (biggest single read; launch first)
    pair_mean_k<<<N, 256, 0, stream>>>(pair, pmean);

    // 1D track: pre-LN MHA
    ln128_k<<<N, 128, 0, stream>>>(seq, ln1g, ln1b, nullptr, xn);
    gemm_rows_k<128, 384, 0><<<N / 4, 256, 0, stream>>>(xn, w_qkv, b_qkv, nullptr, qkvb);
    transposeK_k<384, 128><<<dim3(32, 4), 256, 0, stream>>>(qkvb, kTm);
    mha_attn_k<<<N * NH, 256, 0, stream>>>(qkvb, kTm, abuf);
    gemm_rows_k<128, 128, 0><<<N / 4, 256, 0, stream>>>(abuf, w_o, b_o, seq, x1);

    // pair -> 1D aggregation
    gemm_rows_k<64, 128, 0><<<N / 4, 256, 0, stream>>>(pmean, w_2to1, b_2to1, x1, x2);

    // FFN
    ln128_k<<<N, 128, 0, stream>>>(x2, lnffg, lnffb, nullptr, hdn);
    gemm_rows_k<128, 512, 1><<<N / 4, 256, 0, stream>>>(hdn, w_ff1, b_ff1, nullptr, ff1);
    gemm_rows_k<512, 128, 0><<<N / 4, 256, 0, stream>>>(ff1, w_ff2, b_ff2, x2, xa);

    // fused projections (also writes kTi transposed)
    proj_all_k<<<N / 4, 256, 0, stream>>>(xa, wq, wk, wv, wqp, wkp, wvp,
                                          w_l, b_l, w_r, b_r,
                                          qb, kb, vb, qp, kp, vp, left, right, kTi);

    // pair outer + 1x1 conv via bf16 MFMA (single pass over pair)
    pair_update_mfma_k<<<N, 256, 0, stream>>>(pair, left, right, w_conv, b_conv, out_pair);

    // frames to global + squared sums (kp/kk written transposed)
    to_global_k<<<N, 256, 0, stream>>>(qp, kp, vp, fR, ft, qpg, kpgT, vpg, qqb, kkT);

    // IPA attention
    ipa_attn_k<<<N * NH, 256, 0, stream>>>(qb, vb, kTi, kpgT, kkT, qpg, vpg, qqb, headw,
                                           feat, optg);

    // local frame + norms -> feat tail
    feat_finish_k<<<N, 64, 0, stream>>>(optg, fR, ft, feat);

    // IPA output projection
    gemm_rows_k<192, 128, 0><<<N / 4, 256, 0, stream>>>(feat, wout, bout, nullptr, ipa_out);

    // final residual + post-LN
    ln128_k<<<N, 128, 0, stream>>>(ipa_out, ln3g, ln3b, xa, out_x);

    // frames pass-through
    copy_frames_k<<<48, 256, 0, stream>>>(fR, ft, out_t - 9216);
}